// Round 8
// baseline (188.565 us; speedup 1.0000x reference)
//
#include <hip/hip_runtime.h>
#include <hip/hip_bf16.h>

typedef __hip_bfloat16 bf16;
typedef unsigned short u16;
typedef __attribute__((ext_vector_type(8))) short short8;
typedef __attribute__((ext_vector_type(4))) float floatx4;

#define D_EMBED 1024
#define N_HEADS 16
#define HEAD_DIM 64
#define BATCH 2
#define SEQ 2048
#define ROWS (BATCH * SEQ)          // 4096
#define QKV_COLS (3 * D_EMBED)      // 3072
// exp2-domain scale folded into Q: log2(e)/sqrt(64)
#define QSCALE 0.1803368801f

__device__ __forceinline__ void g2l16(const void* g, void* l) {
    __builtin_amdgcn_global_load_lds(
        (const __attribute__((address_space(1))) unsigned int*)g,
        (__attribute__((address_space(3))) unsigned int*)l,
        16, 0, 0);
}

__device__ __forceinline__ u16 f2b_bits(float f) {
    bf16 h = __float2bfloat16(f);
    u16 u;
    __builtin_memcpy(&u, &h, 2);
    return u;
}

__device__ __forceinline__ unsigned pack2(float a, float b) {   // RNE pack
    return (unsigned)f2b_bits(a) | ((unsigned)f2b_bits(b) << 16);
}

__device__ __forceinline__ float fexp2(float x) {
#if __has_builtin(__builtin_amdgcn_exp2f)
    return __builtin_amdgcn_exp2f(x);
#else
    return exp2f(x);
#endif
}

// pack two fp32 -> two truncated bf16 in one op (low = a, high = b)
__device__ __forceinline__ unsigned permpack(float a, float b) {
#if __has_builtin(__builtin_amdgcn_perm)
    return __builtin_amdgcn_perm(__float_as_uint(b), __float_as_uint(a), 0x07060302u);
#else
    return (__float_as_uint(a) >> 16) | (__float_as_uint(b) & 0xFFFF0000u);
#endif
}

// RNE-convert 8 fp32 (two float4) -> short8 of bf16 bits
__device__ __forceinline__ short8 cvt8(const float4 a, const float4 b) {
    short8 o;
    o[0] = (short)f2b_bits(a.x); o[1] = (short)f2b_bits(a.y);
    o[2] = (short)f2b_bits(a.z); o[3] = (short)f2b_bits(a.w);
    o[4] = (short)f2b_bits(b.x); o[5] = (short)f2b_bits(b.y);
    o[6] = (short)f2b_bits(b.z); o[7] = (short)f2b_bits(b.w);
    return o;
}

// ---------------------------------------------------------------------------
// prep: transpose+cast w_qkv, w_o ONLY (x-cast fused into gemm_qkv staging).
// grid = 768 (wqkv 48x16) + 256 (wo 16x16) = 1024 blocks.
// ---------------------------------------------------------------------------
__global__ __launch_bounds__(256)
void prep(const float* __restrict__ w_qkv, const float* __restrict__ w_o,
          bf16* __restrict__ wqkvT, bf16* __restrict__ woT)
{
    __shared__ u16 T[64][72];
    const int tid = threadIdx.x;
    const int bid = blockIdx.x;

    const float* in; u16* out; int R, C, bx, by;
    if (bid < 768) {
        in = w_qkv; out = reinterpret_cast<u16*>(wqkvT); R = 1024; C = 3072;
        bx = bid % 48; by = bid / 48;
    } else {
        const int t = bid - 768;
        in = w_o; out = reinterpret_cast<u16*>(woT); R = 1024; C = 1024;
        bx = t % 16; by = t / 16;
    }
    const int r0 = by * 64, c0 = bx * 64;
#pragma unroll
    for (int it = 0; it < 4; ++it) {
        const int r = (tid >> 4) + it * 16;
        const int c4 = (tid & 15) * 4;
        const float4 v = *reinterpret_cast<const float4*>(in + (size_t)(r0 + r) * C + c0 + c4);
        T[c4 + 0][r] = f2b_bits(v.x);
        T[c4 + 1][r] = f2b_bits(v.y);
        T[c4 + 2][r] = f2b_bits(v.z);
        T[c4 + 3][r] = f2b_bits(v.w);
    }
    __syncthreads();
#pragma unroll
    for (int it = 0; it < 4; ++it) {
        const int rr = (tid >> 4) + it * 16;
        const int cc4 = (tid & 15) * 4;
        ushort4 o = *reinterpret_cast<const ushort4*>(&T[rr][cc4]);
        *reinterpret_cast<ushort4*>(out + (size_t)(c0 + rr) * R + r0 + cc4) = o;
    }
}

// ---------------------------------------------------------------------------
// QKV MFMA GEMM: C[4096,3072] = x @ Bt^T + bias. 128x128 tile, BK=32, dbuf.
// Round 19: A-operand staged DIRECTLY from fp32 x (T14 async split):
//   - issue 4 float4 loads before compute (issue-early)
//   - RNE-convert + 2x ds_write_b128 after compute, before barrier
//     (write-late; HBM latency hides under the 32 MFMAs)
//   B-operand staging unchanged (g2l16 from pre-transposed wqkvT).
//   LDS layout byte-identical to the old g2l16 pattern (dest tid*16).
// Epilogue: q (scaled) / k row-major bf16; V stored TRANSPOSED into
// vtb[bh*64+d][s] via per-wave LDS column reads.
// ---------------------------------------------------------------------------
__global__ __launch_bounds__(256)
void gemm_qkv(const float* __restrict__ Xf, const bf16* __restrict__ Bt,
              const float* __restrict__ bias,
              bf16* __restrict__ qb, bf16* __restrict__ kb, bf16* __restrict__ vtb)
{
    __shared__ __align__(16) char smem[32768];
    char* BUF0 = smem;            // As 8K + Bs 8K
    char* BUF1 = smem + 16384;

    const int tid = threadIdx.x;
    const int lane = tid & 63, w = tid >> 6;
    const int quad = lane >> 4, l15 = lane & 15;
    const int mw = (w >> 1) * 64, nw = (w & 1) * 64;
    const int blockM = blockIdx.y * 128, blockN = blockIdx.x * 128;

    const int row0 = tid >> 2, ch = tid & 3;
    const int off0 = (tid & ~63) * 16;
    const float* As0 = Xf + (size_t)(blockM + row0) * 1024 + ch * 8;
    const float* As1 = As0 + (size_t)64 * 1024;
    const bf16* Bsrc0 = Bt + (size_t)(blockN + row0) * 1024 + ch * 8;
    const bf16* Bsrc1 = Bsrc0 + (size_t)64 * 1024;

    auto stageA_load = [&](int k0, float4 (&r)[4]) {
        r[0] = *reinterpret_cast<const float4*>(As0 + k0);
        r[1] = *reinterpret_cast<const float4*>(As0 + k0 + 4);
        r[2] = *reinterpret_cast<const float4*>(As1 + k0);
        r[3] = *reinterpret_cast<const float4*>(As1 + k0 + 4);
    };
    auto stageA_write = [&](const float4 (&r)[4], char* buf) {
        *reinterpret_cast<short8*>(buf + tid * 16) = cvt8(r[0], r[1]);
        *reinterpret_cast<short8*>(buf + 4096 + tid * 16) = cvt8(r[2], r[3]);
    };
    auto stageB = [&](int k0, char* buf) {
        g2l16(Bsrc0 + k0, buf + 8192 + off0);
        g2l16(Bsrc1 + k0, buf + 8192 + off0 + 4096);
    };

    floatx4 acc[4][4];
#pragma unroll
    for (int i = 0; i < 4; ++i)
#pragma unroll
        for (int j = 0; j < 4; ++j) acc[i][j] = (floatx4){0.f, 0.f, 0.f, 0.f};

    auto compute = [&](char* buf) {
        short8 af[4], bfr[4];
#pragma unroll
        for (int mi = 0; mi < 4; ++mi)
            af[mi] = *reinterpret_cast<const short8*>(
                buf + (mw + mi * 16 + l15) * 64 + quad * 16);
#pragma unroll
        for (int ni = 0; ni < 4; ++ni)
            bfr[ni] = *reinterpret_cast<const short8*>(
                buf + 8192 + (nw + ni * 16 + l15) * 64 + quad * 16);
#pragma unroll
        for (int mi = 0; mi < 4; ++mi)
#pragma unroll
            for (int ni = 0; ni < 4; ++ni)
                acc[mi][ni] = __builtin_amdgcn_mfma_f32_16x16x32_bf16(
                    af[mi], bfr[ni], acc[mi][ni], 0, 0, 0);
    };

    // prologue: stage k-block 0 into BUF0 (A via regs, B via g2l16)
    {
        float4 r0[4];
        stageA_load(0, r0);
        stageB(0, BUF0);
        stageA_write(r0, BUF0);
    }
    __syncthreads();

    float4 rn[4];
#pragma unroll 1
    for (int k0 = 0; k0 < 1024; k0 += 64) {
        if (k0 + 32 < 1024) { stageA_load(k0 + 32, rn); stageB(k0 + 32, BUF1); }
        compute(BUF0);
        if (k0 + 32 < 1024) stageA_write(rn, BUF1);
        __syncthreads();
        if (k0 + 64 < 1024) { stageA_load(k0 + 64, rn); stageB(k0 + 64, BUF0); }
        compute(BUF1);
        if (k0 + 64 < 1024) stageA_write(rn, BUF0);
        __syncthreads();
    }

    // epilogue: per-wave LDS repack
    u16* W = reinterpret_cast<u16*>(smem + w * 2304);   // [16 m][stride 72 u16]
    const bool isq = (blockN < 1024);
    const bool isv = (blockN >= 2048);

    float bvn[4];
#pragma unroll
    for (int ni = 0; ni < 4; ++ni) bvn[ni] = bias[blockN + nw + ni * 16 + l15];

    if (!isv) {
        bf16* dstbuf = isq ? qb : kb;
        const int coloff = blockN - (isq ? 0 : 1024);
#pragma unroll
        for (int mi = 0; mi < 4; ++mi) {
#pragma unroll
            for (int ni = 0; ni < 4; ++ni) {
#pragma unroll
                for (int r = 0; r < 4; ++r) {
                    float val = acc[mi][ni][r] + bvn[ni];
                    if (isq) val *= QSCALE;
                    W[(quad * 4 + r) * 72 + ni * 16 + l15] = f2b_bits(val);
                }
            }
#pragma unroll
            for (int half = 0; half < 2; ++half) {
                const int idx = half * 64 + lane;
                const int rowL = idx >> 3, chh = idx & 7;
                short8 v = *reinterpret_cast<const short8*>(W + rowL * 72 + chh * 8);
                const int grow = blockM + mw + mi * 16 + rowL;
                const int gcol = coloff + nw + chh * 8;
                *reinterpret_cast<short8*>(
                    reinterpret_cast<u16*>(dstbuf) + (size_t)grow * 1024 + gcol) = v;
            }
        }
    } else {
        const int col0 = blockN - 2048 + nw;          // multiple of 64
        const int h = col0 >> 6;
        const int bh = (blockM >> 11) * 16 + h;
        const int sb = (blockM & 2047) + mw;
        u16* vdst = reinterpret_cast<u16*>(vtb) + (size_t)bh * 64 * SEQ;
#pragma unroll
        for (int mi = 0; mi < 4; ++mi) {
#pragma unroll
            for (int ni = 0; ni < 4; ++ni) {
#pragma unroll
                for (int r = 0; r < 4; ++r)
                    W[(quad * 4 + r) * 72 + ni * 16 + l15] =
                        f2b_bits(acc[mi][ni][r] + bvn[ni]);
            }
#pragma unroll
            for (int mc = 0; mc < 2; ++mc) {
                u16 tmp[8];
#pragma unroll
                for (int e = 0; e < 8; ++e) tmp[e] = W[(mc * 8 + e) * 72 + lane];
                const int s = sb + mi * 16 + mc * 8;
                *reinterpret_cast<short8*>(vdst + (size_t)lane * SEQ + s) =
                    *reinterpret_cast<const short8*>(tmp);
            }
        }
    }
}

// ---------------------------------------------------------------------------
// Out-proj MFMA GEMM: out[4096,1024] = A @ Bt^T + bias (fp32 out).
// 128m x 64n tile -> 512 blocks (2/CU). Double-buffered staging.
// ---------------------------------------------------------------------------
__global__ __launch_bounds__(256)
void gemm_out(const bf16* __restrict__ A, const bf16* __restrict__ Bt,
              const float* __restrict__ bias, float* __restrict__ outf)
{
    __shared__ __align__(16) char smem[24576];
    char* BUF0 = smem;            // As 8K + Bs 4K
    char* BUF1 = smem + 12288;

    const int tid = threadIdx.x;
    const int lane = tid & 63, w = tid >> 6;
    const int quad = lane >> 4, l15 = lane & 15;
    const int mw = (w >> 1) * 64, nw = (w & 1) * 32;
    const int blockM = blockIdx.y * 128, blockN = blockIdx.x * 64;

    const int row0 = tid >> 2, ch = tid & 3;
    const int off0 = (tid & ~63) * 16;
    const bf16* Asrc0 = A + (size_t)(blockM + row0) * 1024 + ch * 8;
    const bf16* Asrc1 = Asrc0 + (size_t)64 * 1024;
    const bf16* Bsrc0 = Bt + (size_t)(blockN + row0) * 1024 + ch * 8;

    auto stage = [&](int k0, char* buf) {
        g2l16(Asrc0 + k0, buf + off0);
        g2l16(Asrc1 + k0, buf + off0 + 4096);
        g2l16(Bsrc0 + k0, buf + 8192 + off0);
    };

    floatx4 acc[4][2];
#pragma unroll
    for (int i = 0; i < 4; ++i)
#pragma unroll
        for (int j = 0; j < 2; ++j) acc[i][j] = (floatx4){0.f, 0.f, 0.f, 0.f};

    auto compute = [&](char* buf) {
        short8 af[4], bfr[2];
#pragma unroll
        for (int mi = 0; mi < 4; ++mi)
            af[mi] = *reinterpret_cast<const short8*>(
                buf + (mw + mi * 16 + l15) * 64 + quad * 16);
#pragma unroll
        for (int ni = 0; ni < 2; ++ni)
            bfr[ni] = *reinterpret_cast<const short8*>(
                buf + 8192 + (nw + ni * 16 + l15) * 64 + quad * 16);
#pragma unroll
        for (int mi = 0; mi < 4; ++mi)
#pragma unroll
            for (int ni = 0; ni < 2; ++ni)
                acc[mi][ni] = __builtin_amdgcn_mfma_f32_16x16x32_bf16(
                    af[mi], bfr[ni], acc[mi][ni], 0, 0, 0);
    };

    stage(0, BUF0);
    __syncthreads();
#pragma unroll 1
    for (int k0 = 0; k0 < 1024; k0 += 64) {
        if (k0 + 32 < 1024) stage(k0 + 32, BUF1);
        compute(BUF0);
        __syncthreads();
        if (k0 + 64 < 1024) stage(k0 + 64, BUF0);
        compute(BUF1);
        __syncthreads();
    }

    float bvn[2];
#pragma unroll
    for (int ni = 0; ni < 2; ++ni) bvn[ni] = bias[blockN + nw + ni * 16 + l15];

#pragma unroll
    for (int mi = 0; mi < 4; ++mi)
#pragma unroll
        for (int r = 0; r < 4; ++r) {
            const int row = blockM + mw + mi * 16 + quad * 4 + r;
#pragma unroll
            for (int ni = 0; ni < 2; ++ni) {
                const int col = blockN + nw + ni * 16 + l15;
                outf[(size_t)row * 1024 + col] = acc[mi][ni][r] + bvn[ni];
            }
        }
}

// ---------------------------------------------------------------------------
// MFMA flash attention (causal), max-free exp2-domain softmax.
// EXACT r6 kernel (best measured: 172.9 us total): merged-pair shell,
// 4-buffer KV pipeline (2 tiles/barrier), setprio, complementary swizzle.
// (r7 wave-specialization was neutral-to-worse; reverted.)
// LDS: 4 x 16K KV + 16K Ps = 80 KB (2 blocks/CU).
// ---------------------------------------------------------------------------
__global__ __launch_bounds__(256)
void attn_mfma(const bf16* __restrict__ qb, const bf16* __restrict__ kb,
               const bf16* __restrict__ vtb, bf16* __restrict__ ob)
{
    __shared__ __align__(16) char smem[81920];
    char* A0 = smem;                      // K 8K + V 8K  (tiles kt%4==0)
    char* A1 = smem + 16384;              // tiles kt%4==1
    char* B0 = smem + 32768;              // tiles kt%4==2 (initially Q staging)
    char* B1 = smem + 49152;              // tiles kt%4==3
    const int tid = threadIdx.x;
    const int lane = tid & 63, w = tid >> 6;
    const int quad = lane >> 4, l15 = lane & 15;
    char* PsB = smem + 65536 + w * 2048;  // per-wave [8 kchunk][16 q][16B]
    char* PsS = smem + 73728 + w * 2048;

    // complementary swizzle: l and l+256 share a CU (round-robin heuristic)
    // slot<8: pi=slot ; slot>=8: pi=23-slot  => KT(l) + KT(l+256) = 49
    const int l = blockIdx.x;
    const int bh = l & 31;
    const int slot = l >> 5;
    const int pi = (slot < 8) ? slot : 23 - slot;
    const int b = bh >> 4, h = bh & 15;

    const int qtS = pi, qtB = 31 - pi;
    const int q0S = qtS * 64, q0B = qtB * 64;
    const int KT = qtB + 1;               // 17..32
    const int qrowS = q0S + w * 16 + l15;
    const int qrowB = q0B + w * 16 + l15;

    const size_t kvrow = (size_t)b * SEQ;
    const size_t vbase = (size_t)bh * 64 * SEQ;

    const short8 ones = {0x3F80, 0x3F80, 0x3F80, 0x3F80,
                         0x3F80, 0x3F80, 0x3F80, 0x3F80};   // bf16 1.0 x8

    // hoisted staging geometry: row1 = row0+32, lch identical (32 % 8 == 0)
    const int row0 = tid >> 3;
    const int lch = (tid & 7) ^ (row0 & 7);
    const int loff0 = (tid & ~63) * 16;
    const int loff1 = loff0 + 4096;
    const bf16* ksrc0 = kb + (kvrow + row0) * D_EMBED + h * 64 + lch * 8;
    const bf16* ksrc1 = ksrc0 + (size_t)32 * D_EMBED;
    const bf16* vsrc0 = vtb + vbase + (size_t)row0 * SEQ + lch * 8;
    const bf16* vsrc1 = vsrc0 + (size_t)32 * SEQ;

    auto prefetch = [&](int nkt, char* dst) {
        const size_t ko = (size_t)nkt * 64;
        g2l16(ksrc0 + ko * D_EMBED, dst + loff0);
        g2l16(ksrc1 + ko * D_EMBED, dst + loff1);
        g2l16(vsrc0 + ko, dst + 8192 + loff0);
        g2l16(vsrc1 + ko, dst + 8192 + loff1);
    };

    // stage Q tiles into B0 (dead after fragment load) + K/V tiles 0,1
    {
        const bf16* qsrcS = qb + (kvrow + q0S + row0) * D_EMBED + h * 64 + lch * 8;
        const bf16* qsrcB = qb + (kvrow + q0B + row0) * D_EMBED + h * 64 + lch * 8;
        g2l16(qsrcS, B0 + loff0);
        g2l16(qsrcS + (size_t)32 * D_EMBED, B0 + loff1);
        g2l16(qsrcB, B0 + 8192 + loff0);
        g2l16(qsrcB + (size_t)32 * D_EMBED, B0 + 8192 + loff1);
        prefetch(0, A0);
        prefetch(1, A1);          // KT >= 17, tile 1 always exists
    }
    __syncthreads();

    const int qoff = (w * 16 + l15) * 128;
    const int x0 = (quad ^ (l15 & 7)) * 16;
    const int x1 = ((quad + 4) ^ (l15 & 7)) * 16;
    const short8 qS0 = *reinterpret_cast<const short8*>(B0 + qoff + x0);
    const short8 qS1 = *reinterpret_cast<const short8*>(B0 + qoff + x1);
    const short8 qB0 = *reinterpret_cast<const short8*>(B0 + 8192 + qoff + x0);
    const short8 qB1 = *reinterpret_cast<const short8*>(B0 + 8192 + qoff + x1);
    __syncthreads();    // Q reads done; B0 free for prefetch

    floatx4 OaccS[4], OaccB[4], LaccS, LaccB;
#pragma unroll
    for (int i = 0; i < 4; ++i) {
        OaccS[i] = (floatx4){0.f, 0.f, 0.f, 0.f};
        OaccB[i] = (floatx4){0.f, 0.f, 0.f, 0.f};
    }
    LaccS = (floatx4){0.f, 0.f, 0.f, 0.f};
    LaccB = (floatx4){0.f, 0.f, 0.f, 0.f};

    // interleaved dual-q compute: both chains issued together
    auto compute = [&](int kt, char* Ks, char* Vs) {
        const int k0 = kt * 64;
        const bool doS = (kt <= qtS);
        short8 kf[2][4], vf[2][4];
#pragma unroll
        for (int ms = 0; ms < 4; ++ms) {
            const int roff = (ms * 16 + l15) * 128;
            kf[0][ms] = *reinterpret_cast<const short8*>(Ks + roff + x0);
            kf[1][ms] = *reinterpret_cast<const short8*>(Ks + roff + x1);
        }
#pragma unroll
        for (int ks = 0; ks < 2; ++ks)
#pragma unroll
            for (int ds = 0; ds < 4; ++ds)
                vf[ks][ds] = *reinterpret_cast<const short8*>(
                    Vs + (ds * 16 + l15) * 128 + (((quad + ks * 4) ^ (l15 & 7)) * 16));

        // S MFMAs for both tiles (independent)
        floatx4 SB[4], SS[4];
        __builtin_amdgcn_s_setprio(1);
#pragma unroll
        for (int ms = 0; ms < 4; ++ms) {
            floatx4 t = (floatx4){0.f, 0.f, 0.f, 0.f};
            t = __builtin_amdgcn_mfma_f32_16x16x32_bf16(kf[0][ms], qB0, t, 0, 0, 0);
            SB[ms] = __builtin_amdgcn_mfma_f32_16x16x32_bf16(kf[1][ms], qB1, t, 0, 0, 0);
        }
        if (doS) {
#pragma unroll
            for (int ms = 0; ms < 4; ++ms) {
                floatx4 t = (floatx4){0.f, 0.f, 0.f, 0.f};
                t = __builtin_amdgcn_mfma_f32_16x16x32_bf16(kf[0][ms], qS0, t, 0, 0, 0);
                SS[ms] = __builtin_amdgcn_mfma_f32_16x16x32_bf16(kf[1][ms], qS1, t, 0, 0, 0);
            }
        }
        __builtin_amdgcn_s_setprio(0);

        // exp + Ps writes: big -> PsB, small -> PsS (disjoint regions)
        const bool diagB = (kt == KT - 1);
#pragma unroll
        for (int ms = 0; ms < 4; ++ms) {
            float p[4];
#pragma unroll
            for (int r = 0; r < 4; ++r) {
                float s = SB[ms][r];
                if (diagB && (k0 + ms * 16 + quad * 4 + r) > qrowB) s = -1e30f;
                p[r] = fexp2(s);
            }
            const int k = ms * 16 + quad * 4;
            uint2 pw;
            pw.x = permpack(p[0], p[1]);
            pw.y = permpack(p[2], p[3]);
            *reinterpret_cast<uint2*>(PsB + (k >> 3) * 256 + l15 * 16 + (k & 7) * 2) = pw;
        }
        if (doS) {
            const bool diagS = (kt == qtS);
#pragma unroll
            for (int ms = 0; ms < 4; ++ms) {
                float p[4];
#pragma unroll
                for (int r = 0; r < 4; ++r) {
                    float s = SS[ms][r];
                    if (diagS && (k0 + ms * 16 + quad * 4 + r) > qrowS) s = -1e30f;
                    p[r] = fexp2(s);
                }
                const int k = ms * 16 + quad * 4;
                uint2 pw;
                pw.x = permpack(p[0], p[1]);
                pw.y = permpack(p[2], p[3]);
                *reinterpret_cast<uint2*>(PsS + (k >> 3) * 256 + l15 * 16 + (k & 7) * 2) = pw;
            }
        }

        // O MFMAs, both chains interleaved
        __builtin_amdgcn_s_setprio(1);
#pragma unroll
        for (int ks = 0; ks < 2; ++ks) {
            const short8 pfB = *reinterpret_cast<const short8*>(
                PsB + (ks * 4 + quad) * 256 + l15 * 16);
            LaccB = __builtin_amdgcn_mfma_f32_16x16x32_bf16(ones, pfB, LaccB, 0, 0, 0);
#pragma unroll
            for (int ds = 0; ds < 4; ++ds)
                OaccB[ds] = __builtin_amdgcn_mfma_f32_16x16x32_bf16(
                    vf[ks][ds], pfB, OaccB[ds], 0, 0, 0);
            if (doS) {
                const short8 pfS = *reinterpret_cast<const short8*>(
                    PsS + (ks * 4 + quad) * 256 + l15 * 16);
                LaccS = __builtin_amdgcn_mfma_f32_16x16x32_bf16(ones, pfS, LaccS, 0, 0, 0);
#pragma unroll
                for (int ds = 0; ds < 4; ++ds)
                    OaccS[ds] = __builtin_amdgcn_mfma_f32_16x16x32_bf16(
                        vf[ks][ds], pfS, OaccS[ds], 0, 0, 0);
            }
        }
        __builtin_amdgcn_s_setprio(0);
    };

    // k-loop: 4 tiles / iteration, 2 barriers / iteration (~0.5 barrier/tile)
#pragma unroll 1
    for (int kt = 0; kt < KT; kt += 4) {
        if (kt + 2 < KT) prefetch(kt + 2, B0);
        if (kt + 3 < KT) prefetch(kt + 3, B1);
        compute(kt, A0, A0 + 8192);
        if (kt + 1 < KT) compute(kt + 1, A1, A1 + 8192);
        __syncthreads();
        if (kt + 2 >= KT) break;
        if (kt + 4 < KT) prefetch(kt + 4, A0);
        if (kt + 5 < KT) prefetch(kt + 5, A1);
        compute(kt + 2, B0, B0 + 8192);
        if (kt + 3 < KT) compute(kt + 3, B1, B1 + 8192);
        __syncthreads();
    }

    // epilogue: O^T/l -> per-wave LDS [q][d] -> coalesced 16B stores
#pragma unroll
    for (int which = 0; which < 2; ++which) {
        const floatx4* Oacc = which ? OaccB : OaccS;
        const float invl = 1.f / (which ? LaccB[0] : LaccS[0]);
        const int q0 = which ? q0B : q0S;
#pragma unroll
        for (int ds = 0; ds < 4; ++ds) {
            const int d = ds * 16 + quad * 4;
            uint2 ow;
            ow.x = pack2(Oacc[ds][0] * invl, Oacc[ds][1] * invl);
            ow.y = pack2(Oacc[ds][2] * invl, Oacc[ds][3] * invl);
            *reinterpret_cast<uint2*>(
                PsB + (d >> 3) * 256 + l15 * 16 + (d & 7) * 2) = ow;
        }
#pragma unroll
        for (int it = 0; it < 2; ++it) {
            const int idx = it * 64 + lane;
            const int chh = idx >> 4, q = idx & 15;
            short8 ov = *reinterpret_cast<const short8*>(PsB + chh * 256 + q * 16);
            *reinterpret_cast<short8*>(
                ob + (kvrow + q0 + w * 16 + q) * D_EMBED + h * 64 + chh * 8) = ov;
        }
    }
}

// ---------------------------------------------------------------------------
extern "C" void kernel_launch(void* const* d_in, const int* in_sizes, int n_in,
                              void* d_out, int out_size, void* d_ws, size_t ws_size,
                              hipStream_t stream)
{
    const float* x     = (const float*)d_in[0];   // [4096, 1024]
    const float* w_qkv = (const float*)d_in[1];   // [1024, 3072]
    const float* b_qkv = (const float*)d_in[2];   // [3072]
    const float* w_o   = (const float*)d_in[3];   // [1024, 1024]
    const float* b_o   = (const float*)d_in[4];   // [1024]
    float* out = (float*)d_out;                   // [4096, 1024] fp32

    bf16* wqkvT  = (bf16*)d_ws;                    // [3072][1024]
    bf16* woT    = wqkvT + (size_t)3072 * 1024;    // [1024][1024]
    bf16* qbuf   = woT + (size_t)1024 * 1024;      // [4096][1024] (pre-scaled)
    bf16* kbuf   = qbuf + (size_t)4096 * 1024;     // [4096][1024]
    bf16* vtb    = kbuf + (size_t)4096 * 1024;     // [32 bh][64 d][2048 s]
    bf16* attnb  = vtb + (size_t)4096 * 1024;      // [4096][1024]

    dim3 blk(256);

    // weight transpose+cast only (x-cast fused into gemm_qkv)
    prep<<<dim3(1024), blk, 0, stream>>>(w_qkv, w_o, wqkvT, woT);

    // QKV projection from fp32 x (reg-staged A with RNE convert, T14 split)
    gemm_qkv<<<dim3(24, 32), blk, 0, stream>>>(x, wqkvT, b_qkv, qbuf, kbuf, vtb);

    // flash attention: merged-pair causal blocks, dual-Ps interleave,
    // 4-buffer KV pipeline (2 tiles/barrier), setprio, complementary swizzle
    attn_mfma<<<dim3(512), blk, 0, stream>>>(qbuf, kbuf, vtb, attnb);

    // output projection (fp32 out + bias), 512 blocks, dbuf
    gemm_out<<<dim3(16, 32), blk, 0, stream>>>(attnb, woT, b_o, out);
}

// Round 9
// 173.427 us; speedup vs baseline: 1.0873x; 1.0873x over previous
//
#include <hip/hip_runtime.h>
#include <hip/hip_bf16.h>

typedef __hip_bfloat16 bf16;
typedef unsigned short u16;
typedef __attribute__((ext_vector_type(8))) short short8;
typedef __attribute__((ext_vector_type(4))) float floatx4;

#define D_EMBED 1024
#define N_HEADS 16
#define HEAD_DIM 64
#define BATCH 2
#define SEQ 2048
#define ROWS (BATCH * SEQ)          // 4096
#define QKV_COLS (3 * D_EMBED)      // 3072
// exp2-domain scale folded into Q: log2(e)/sqrt(64)
#define QSCALE 0.1803368801f

__device__ __forceinline__ void g2l16(const void* g, void* l) {
    __builtin_amdgcn_global_load_lds(
        (const __attribute__((address_space(1))) unsigned int*)g,
        (__attribute__((address_space(3))) unsigned int*)l,
        16, 0, 0);
}

__device__ __forceinline__ u16 f2b_bits(float f) {
    bf16 h = __float2bfloat16(f);
    u16 u;
    __builtin_memcpy(&u, &h, 2);
    return u;
}

__device__ __forceinline__ unsigned pack2(float a, float b) {   // RNE pack
    return (unsigned)f2b_bits(a) | ((unsigned)f2b_bits(b) << 16);
}

__device__ __forceinline__ float fexp2(float x) {
#if __has_builtin(__builtin_amdgcn_exp2f)
    return __builtin_amdgcn_exp2f(x);
#else
    return exp2f(x);
#endif
}

// pack two fp32 -> two truncated bf16 in one op (low = a, high = b)
__device__ __forceinline__ unsigned permpack(float a, float b) {
#if __has_builtin(__builtin_amdgcn_perm)
    return __builtin_amdgcn_perm(__float_as_uint(b), __float_as_uint(a), 0x07060302u);
#else
    return (__float_as_uint(a) >> 16) | (__float_as_uint(b) & 0xFFFF0000u);
#endif
}

// ---------------------------------------------------------------------------
// Fused prep: cast x -> bf16 (grid-stride, 4 float4/thread); transpose+cast
// w_qkv, w_o. Grid = 1024 (x-cast) + 1024 (weights) = 2048 blocks.
// Round 9: x-cast granularity fix only — 4096 tiny blocks (1 float4/thread)
// were launch/ramp-bound at ~2.2 TB/s; grid-stride x4 approaches BW floor.
// ---------------------------------------------------------------------------
__global__ __launch_bounds__(256)
void prep(const float* __restrict__ x, const float* __restrict__ w_qkv,
          const float* __restrict__ w_o, bf16* __restrict__ xb,
          bf16* __restrict__ wqkvT, bf16* __restrict__ woT)
{
    __shared__ u16 T[64][72];
    const int tid = threadIdx.x;
    const int bid = blockIdx.x;

    if (bid < 1024) {
        // x-cast: 1024 blocks x 256 threads x 4 float4 = 4096*1024 floats
        const int t0 = bid * 256 + tid;
#pragma unroll
        for (int it = 0; it < 4; ++it) {
            const int i = t0 + it * 262144;
            const float4 v = reinterpret_cast<const float4*>(x)[i];
            ushort4 o;
            o.x = f2b_bits(v.x); o.y = f2b_bits(v.y);
            o.z = f2b_bits(v.z); o.w = f2b_bits(v.w);
            reinterpret_cast<ushort4*>(xb)[i] = o;
        }
        return;
    }
    const float* in; u16* out; int R, C, bx, by;
    if (bid < 1792) {
        const int t = bid - 1024;
        in = w_qkv; out = reinterpret_cast<u16*>(wqkvT); R = 1024; C = 3072;
        bx = t % 48; by = t / 48;
    } else {
        const int t = bid - 1792;
        in = w_o; out = reinterpret_cast<u16*>(woT); R = 1024; C = 1024;
        bx = t % 16; by = t / 16;
    }
    const int r0 = by * 64, c0 = bx * 64;
#pragma unroll
    for (int it = 0; it < 4; ++it) {
        const int r = (tid >> 4) + it * 16;
        const int c4 = (tid & 15) * 4;
        const float4 v = *reinterpret_cast<const float4*>(in + (size_t)(r0 + r) * C + c0 + c4);
        T[c4 + 0][r] = f2b_bits(v.x);
        T[c4 + 1][r] = f2b_bits(v.y);
        T[c4 + 2][r] = f2b_bits(v.z);
        T[c4 + 3][r] = f2b_bits(v.w);
    }
    __syncthreads();
#pragma unroll
    for (int it = 0; it < 4; ++it) {
        const int rr = (tid >> 4) + it * 16;
        const int cc4 = (tid & 15) * 4;
        ushort4 o = *reinterpret_cast<const ushort4*>(&T[rr][cc4]);
        *reinterpret_cast<ushort4*>(out + (size_t)(c0 + rr) * R + r0 + cc4) = o;
    }
}

// ---------------------------------------------------------------------------
// QKV MFMA GEMM: C[4096,3072] = A @ Bt^T + bias. 128x128 tile, BK=32,
// double-buffered staging (r6 version, g2l16 A from pre-cast xb).
// Epilogue: q (scaled) / k row-major bf16; V stored TRANSPOSED into
// vtb[bh*64+d][s] via per-wave LDS column reads.
// ---------------------------------------------------------------------------
__global__ __launch_bounds__(256)
void gemm_qkv(const bf16* __restrict__ A, const bf16* __restrict__ Bt,
              const float* __restrict__ bias,
              bf16* __restrict__ qb, bf16* __restrict__ kb, bf16* __restrict__ vtb)
{
    __shared__ __align__(16) char smem[32768];
    char* BUF0 = smem;            // As 8K + Bs 8K
    char* BUF1 = smem + 16384;

    const int tid = threadIdx.x;
    const int lane = tid & 63, w = tid >> 6;
    const int quad = lane >> 4, l15 = lane & 15;
    const int mw = (w >> 1) * 64, nw = (w & 1) * 64;
    const int blockM = blockIdx.y * 128, blockN = blockIdx.x * 128;

    const int row0 = tid >> 2, ch = tid & 3;
    const int off0 = (tid & ~63) * 16;
    const bf16* Asrc0 = A + (size_t)(blockM + row0) * 1024 + ch * 8;
    const bf16* Asrc1 = Asrc0 + (size_t)64 * 1024;
    const bf16* Bsrc0 = Bt + (size_t)(blockN + row0) * 1024 + ch * 8;
    const bf16* Bsrc1 = Bsrc0 + (size_t)64 * 1024;

    auto stage = [&](int k0, char* buf) {
        g2l16(Asrc0 + k0, buf + off0);
        g2l16(Asrc1 + k0, buf + off0 + 4096);
        g2l16(Bsrc0 + k0, buf + 8192 + off0);
        g2l16(Bsrc1 + k0, buf + 8192 + off0 + 4096);
    };

    floatx4 acc[4][4];
#pragma unroll
    for (int i = 0; i < 4; ++i)
#pragma unroll
        for (int j = 0; j < 4; ++j) acc[i][j] = (floatx4){0.f, 0.f, 0.f, 0.f};

    auto compute = [&](char* buf) {
        short8 af[4], bfr[4];
#pragma unroll
        for (int mi = 0; mi < 4; ++mi)
            af[mi] = *reinterpret_cast<const short8*>(
                buf + (mw + mi * 16 + l15) * 64 + quad * 16);
#pragma unroll
        for (int ni = 0; ni < 4; ++ni)
            bfr[ni] = *reinterpret_cast<const short8*>(
                buf + 8192 + (nw + ni * 16 + l15) * 64 + quad * 16);
#pragma unroll
        for (int mi = 0; mi < 4; ++mi)
#pragma unroll
            for (int ni = 0; ni < 4; ++ni)
                acc[mi][ni] = __builtin_amdgcn_mfma_f32_16x16x32_bf16(
                    af[mi], bfr[ni], acc[mi][ni], 0, 0, 0);
    };

    stage(0, BUF0);
    __syncthreads();
#pragma unroll 1
    for (int k0 = 0; k0 < 1024; k0 += 64) {
        if (k0 + 32 < 1024) stage(k0 + 32, BUF1);
        compute(BUF0);
        __syncthreads();
        if (k0 + 64 < 1024) stage(k0 + 64, BUF0);
        compute(BUF1);
        __syncthreads();
    }

    // epilogue: per-wave LDS repack
    u16* W = reinterpret_cast<u16*>(smem + w * 2304);   // [16 m][stride 72 u16]
    const bool isq = (blockN < 1024);
    const bool isv = (blockN >= 2048);

    float bvn[4];
#pragma unroll
    for (int ni = 0; ni < 4; ++ni) bvn[ni] = bias[blockN + nw + ni * 16 + l15];

    if (!isv) {
        bf16* dstbuf = isq ? qb : kb;
        const int coloff = blockN - (isq ? 0 : 1024);
#pragma unroll
        for (int mi = 0; mi < 4; ++mi) {
#pragma unroll
            for (int ni = 0; ni < 4; ++ni) {
#pragma unroll
                for (int r = 0; r < 4; ++r) {
                    float val = acc[mi][ni][r] + bvn[ni];
                    if (isq) val *= QSCALE;
                    W[(quad * 4 + r) * 72 + ni * 16 + l15] = f2b_bits(val);
                }
            }
#pragma unroll
            for (int half = 0; half < 2; ++half) {
                const int idx = half * 64 + lane;
                const int rowL = idx >> 3, chh = idx & 7;
                short8 v = *reinterpret_cast<const short8*>(W + rowL * 72 + chh * 8);
                const int grow = blockM + mw + mi * 16 + rowL;
                const int gcol = coloff + nw + chh * 8;
                *reinterpret_cast<short8*>(
                    reinterpret_cast<u16*>(dstbuf) + (size_t)grow * 1024 + gcol) = v;
            }
        }
    } else {
        const int col0 = blockN - 2048 + nw;          // multiple of 64
        const int h = col0 >> 6;
        const int bh = (blockM >> 11) * 16 + h;
        const int sb = (blockM & 2047) + mw;
        u16* vdst = reinterpret_cast<u16*>(vtb) + (size_t)bh * 64 * SEQ;
#pragma unroll
        for (int mi = 0; mi < 4; ++mi) {
#pragma unroll
            for (int ni = 0; ni < 4; ++ni) {
#pragma unroll
                for (int r = 0; r < 4; ++r)
                    W[(quad * 4 + r) * 72 + ni * 16 + l15] =
                        f2b_bits(acc[mi][ni][r] + bvn[ni]);
            }
#pragma unroll
            for (int mc = 0; mc < 2; ++mc) {
                u16 tmp[8];
#pragma unroll
                for (int e = 0; e < 8; ++e) tmp[e] = W[(mc * 8 + e) * 72 + lane];
                const int s = sb + mi * 16 + mc * 8;
                *reinterpret_cast<short8*>(vdst + (size_t)lane * SEQ + s) =
                    *reinterpret_cast<const short8*>(tmp);
            }
        }
    }
}

// ---------------------------------------------------------------------------
// Out-proj MFMA GEMM: out[4096,1024] = A @ Bt^T + bias (fp32 out).
// 128m x 64n tile -> 512 blocks (2/CU). Double-buffered staging.
// ---------------------------------------------------------------------------
__global__ __launch_bounds__(256)
void gemm_out(const bf16* __restrict__ A, const bf16* __restrict__ Bt,
              const float* __restrict__ bias, float* __restrict__ outf)
{
    __shared__ __align__(16) char smem[24576];
    char* BUF0 = smem;            // As 8K + Bs 4K
    char* BUF1 = smem + 12288;

    const int tid = threadIdx.x;
    const int lane = tid & 63, w = tid >> 6;
    const int quad = lane >> 4, l15 = lane & 15;
    const int mw = (w >> 1) * 64, nw = (w & 1) * 32;
    const int blockM = blockIdx.y * 128, blockN = blockIdx.x * 64;

    const int row0 = tid >> 2, ch = tid & 3;
    const int off0 = (tid & ~63) * 16;
    const bf16* Asrc0 = A + (size_t)(blockM + row0) * 1024 + ch * 8;
    const bf16* Asrc1 = Asrc0 + (size_t)64 * 1024;
    const bf16* Bsrc0 = Bt + (size_t)(blockN + row0) * 1024 + ch * 8;

    auto stage = [&](int k0, char* buf) {
        g2l16(Asrc0 + k0, buf + off0);
        g2l16(Asrc1 + k0, buf + off0 + 4096);
        g2l16(Bsrc0 + k0, buf + 8192 + off0);
    };

    floatx4 acc[4][2];
#pragma unroll
    for (int i = 0; i < 4; ++i)
#pragma unroll
        for (int j = 0; j < 2; ++j) acc[i][j] = (floatx4){0.f, 0.f, 0.f, 0.f};

    auto compute = [&](char* buf) {
        short8 af[4], bfr[2];
#pragma unroll
        for (int mi = 0; mi < 4; ++mi)
            af[mi] = *reinterpret_cast<const short8*>(
                buf + (mw + mi * 16 + l15) * 64 + quad * 16);
#pragma unroll
        for (int ni = 0; ni < 2; ++ni)
            bfr[ni] = *reinterpret_cast<const short8*>(
                buf + 8192 + (nw + ni * 16 + l15) * 64 + quad * 16);
#pragma unroll
        for (int mi = 0; mi < 4; ++mi)
#pragma unroll
            for (int ni = 0; ni < 2; ++ni)
                acc[mi][ni] = __builtin_amdgcn_mfma_f32_16x16x32_bf16(
                    af[mi], bfr[ni], acc[mi][ni], 0, 0, 0);
    };

    stage(0, BUF0);
    __syncthreads();
#pragma unroll 1
    for (int k0 = 0; k0 < 1024; k0 += 64) {
        if (k0 + 32 < 1024) stage(k0 + 32, BUF1);
        compute(BUF0);
        __syncthreads();
        if (k0 + 64 < 1024) stage(k0 + 64, BUF0);
        compute(BUF1);
        __syncthreads();
    }

    float bvn[2];
#pragma unroll
    for (int ni = 0; ni < 2; ++ni) bvn[ni] = bias[blockN + nw + ni * 16 + l15];

#pragma unroll
    for (int mi = 0; mi < 4; ++mi)
#pragma unroll
        for (int r = 0; r < 4; ++r) {
            const int row = blockM + mw + mi * 16 + quad * 4 + r;
#pragma unroll
            for (int ni = 0; ni < 2; ++ni) {
                const int col = blockN + nw + ni * 16 + l15;
                outf[(size_t)row * 1024 + col] = acc[mi][ni][r] + bvn[ni];
            }
        }
}

// ---------------------------------------------------------------------------
// MFMA flash attention (causal), max-free exp2-domain softmax.
// EXACT r6 kernel (best measured: 172.9 us total): merged-pair shell,
// 4-buffer KV pipeline (2 tiles/barrier), setprio, complementary swizzle.
// LDS: 4 x 16K KV + 16K Ps = 80 KB (2 blocks/CU).
// ---------------------------------------------------------------------------
__global__ __launch_bounds__(256)
void attn_mfma(const bf16* __restrict__ qb, const bf16* __restrict__ kb,
               const bf16* __restrict__ vtb, bf16* __restrict__ ob)
{
    __shared__ __align__(16) char smem[81920];
    char* A0 = smem;                      // K 8K + V 8K  (tiles kt%4==0)
    char* A1 = smem + 16384;              // tiles kt%4==1
    char* B0 = smem + 32768;              // tiles kt%4==2 (initially Q staging)
    char* B1 = smem + 49152;              // tiles kt%4==3
    const int tid = threadIdx.x;
    const int lane = tid & 63, w = tid >> 6;
    const int quad = lane >> 4, l15 = lane & 15;
    char* PsB = smem + 65536 + w * 2048;  // per-wave [8 kchunk][16 q][16B]
    char* PsS = smem + 73728 + w * 2048;

    // complementary swizzle: l and l+256 share a CU (round-robin heuristic)
    // slot<8: pi=slot ; slot>=8: pi=23-slot  => KT(l) + KT(l+256) = 49
    const int l = blockIdx.x;
    const int bh = l & 31;
    const int slot = l >> 5;
    const int pi = (slot < 8) ? slot : 23 - slot;
    const int b = bh >> 4, h = bh & 15;

    const int qtS = pi, qtB = 31 - pi;
    const int q0S = qtS * 64, q0B = qtB * 64;
    const int KT = qtB + 1;               // 17..32
    const int qrowS = q0S + w * 16 + l15;
    const int qrowB = q0B + w * 16 + l15;

    const size_t kvrow = (size_t)b * SEQ;
    const size_t vbase = (size_t)bh * 64 * SEQ;

    const short8 ones = {0x3F80, 0x3F80, 0x3F80, 0x3F80,
                         0x3F80, 0x3F80, 0x3F80, 0x3F80};   // bf16 1.0 x8

    // hoisted staging geometry: row1 = row0+32, lch identical (32 % 8 == 0)
    const int row0 = tid >> 3;
    const int lch = (tid & 7) ^ (row0 & 7);
    const int loff0 = (tid & ~63) * 16;
    const int loff1 = loff0 + 4096;
    const bf16* ksrc0 = kb + (kvrow + row0) * D_EMBED + h * 64 + lch * 8;
    const bf16* ksrc1 = ksrc0 + (size_t)32 * D_EMBED;
    const bf16* vsrc0 = vtb + vbase + (size_t)row0 * SEQ + lch * 8;
    const bf16* vsrc1 = vsrc0 + (size_t)32 * SEQ;

    auto prefetch = [&](int nkt, char* dst) {
        const size_t ko = (size_t)nkt * 64;
        g2l16(ksrc0 + ko * D_EMBED, dst + loff0);
        g2l16(ksrc1 + ko * D_EMBED, dst + loff1);
        g2l16(vsrc0 + ko, dst + 8192 + loff0);
        g2l16(vsrc1 + ko, dst + 8192 + loff1);
    };

    // stage Q tiles into B0 (dead after fragment load) + K/V tiles 0,1
    {
        const bf16* qsrcS = qb + (kvrow + q0S + row0) * D_EMBED + h * 64 + lch * 8;
        const bf16* qsrcB = qb + (kvrow + q0B + row0) * D_EMBED + h * 64 + lch * 8;
        g2l16(qsrcS, B0 + loff0);
        g2l16(qsrcS + (size_t)32 * D_EMBED, B0 + loff1);
        g2l16(qsrcB, B0 + 8192 + loff0);
        g2l16(qsrcB + (size_t)32 * D_EMBED, B0 + 8192 + loff1);
        prefetch(0, A0);
        prefetch(1, A1);          // KT >= 17, tile 1 always exists
    }
    __syncthreads();

    const int qoff = (w * 16 + l15) * 128;
    const int x0 = (quad ^ (l15 & 7)) * 16;
    const int x1 = ((quad + 4) ^ (l15 & 7)) * 16;
    const short8 qS0 = *reinterpret_cast<const short8*>(B0 + qoff + x0);
    const short8 qS1 = *reinterpret_cast<const short8*>(B0 + qoff + x1);
    const short8 qB0 = *reinterpret_cast<const short8*>(B0 + 8192 + qoff + x0);
    const short8 qB1 = *reinterpret_cast<const short8*>(B0 + 8192 + qoff + x1);
    __syncthreads();    // Q reads done; B0 free for prefetch

    floatx4 OaccS[4], OaccB[4], LaccS, LaccB;
#pragma unroll
    for (int i = 0; i < 4; ++i) {
        OaccS[i] = (floatx4){0.f, 0.f, 0.f, 0.f};
        OaccB[i] = (floatx4){0.f, 0.f, 0.f, 0.f};
    }
    LaccS = (floatx4){0.f, 0.f, 0.f, 0.f};
    LaccB = (floatx4){0.f, 0.f, 0.f, 0.f};

    // interleaved dual-q compute: both chains issued together
    auto compute = [&](int kt, char* Ks, char* Vs) {
        const int k0 = kt * 64;
        const bool doS = (kt <= qtS);
        short8 kf[2][4], vf[2][4];
#pragma unroll
        for (int ms = 0; ms < 4; ++ms) {
            const int roff = (ms * 16 + l15) * 128;
            kf[0][ms] = *reinterpret_cast<const short8*>(Ks + roff + x0);
            kf[1][ms] = *reinterpret_cast<const short8*>(Ks + roff + x1);
        }
#pragma unroll
        for (int ks = 0; ks < 2; ++ks)
#pragma unroll
            for (int ds = 0; ds < 4; ++ds)
                vf[ks][ds] = *reinterpret_cast<const short8*>(
                    Vs + (ds * 16 + l15) * 128 + (((quad + ks * 4) ^ (l15 & 7)) * 16));

        // S MFMAs for both tiles (independent)
        floatx4 SB[4], SS[4];
        __builtin_amdgcn_s_setprio(1);
#pragma unroll
        for (int ms = 0; ms < 4; ++ms) {
            floatx4 t = (floatx4){0.f, 0.f, 0.f, 0.f};
            t = __builtin_amdgcn_mfma_f32_16x16x32_bf16(kf[0][ms], qB0, t, 0, 0, 0);
            SB[ms] = __builtin_amdgcn_mfma_f32_16x16x32_bf16(kf[1][ms], qB1, t, 0, 0, 0);
        }
        if (doS) {
#pragma unroll
            for (int ms = 0; ms < 4; ++ms) {
                floatx4 t = (floatx4){0.f, 0.f, 0.f, 0.f};
                t = __builtin_amdgcn_mfma_f32_16x16x32_bf16(kf[0][ms], qS0, t, 0, 0, 0);
                SS[ms] = __builtin_amdgcn_mfma_f32_16x16x32_bf16(kf[1][ms], qS1, t, 0, 0, 0);
            }
        }
        __builtin_amdgcn_s_setprio(0);

        // exp + Ps writes: big -> PsB, small -> PsS (disjoint regions)
        const bool diagB = (kt == KT - 1);
#pragma unroll
        for (int ms = 0; ms < 4; ++ms) {
            float p[4];
#pragma unroll
            for (int r = 0; r < 4; ++r) {
                float s = SB[ms][r];
                if (diagB && (k0 + ms * 16 + quad * 4 + r) > qrowB) s = -1e30f;
                p[r] = fexp2(s);
            }
            const int k = ms * 16 + quad * 4;
            uint2 pw;
            pw.x = permpack(p[0], p[1]);
            pw.y = permpack(p[2], p[3]);
            *reinterpret_cast<uint2*>(PsB + (k >> 3) * 256 + l15 * 16 + (k & 7) * 2) = pw;
        }
        if (doS) {
            const bool diagS = (kt == qtS);
#pragma unroll
            for (int ms = 0; ms < 4; ++ms) {
                float p[4];
#pragma unroll
                for (int r = 0; r < 4; ++r) {
                    float s = SS[ms][r];
                    if (diagS && (k0 + ms * 16 + quad * 4 + r) > qrowS) s = -1e30f;
                    p[r] = fexp2(s);
                }
                const int k = ms * 16 + quad * 4;
                uint2 pw;
                pw.x = permpack(p[0], p[1]);
                pw.y = permpack(p[2], p[3]);
                *reinterpret_cast<uint2*>(PsS + (k >> 3) * 256 + l15 * 16 + (k & 7) * 2) = pw;
            }
        }

        // O MFMAs, both chains interleaved
        __builtin_amdgcn_s_setprio(1);
#pragma unroll
        for (int ks = 0; ks < 2; ++ks) {
            const short8 pfB = *reinterpret_cast<const short8*>(
                PsB + (ks * 4 + quad) * 256 + l15 * 16);
            LaccB = __builtin_amdgcn_mfma_f32_16x16x32_bf16(ones, pfB, LaccB, 0, 0, 0);
#pragma unroll
            for (int ds = 0; ds < 4; ++ds)
                OaccB[ds] = __builtin_amdgcn_mfma_f32_16x16x32_bf16(
                    vf[ks][ds], pfB, OaccB[ds], 0, 0, 0);
            if (doS) {
                const short8 pfS = *reinterpret_cast<const short8*>(
                    PsS + (ks * 4 + quad) * 256 + l15 * 16);
                LaccS = __builtin_amdgcn_mfma_f32_16x16x32_bf16(ones, pfS, LaccS, 0, 0, 0);
#pragma unroll
                for (int ds = 0; ds < 4; ++ds)
                    OaccS[ds] = __builtin_amdgcn_mfma_f32_16x16x32_bf16(
                        vf[ks][ds], pfS, OaccS[ds], 0, 0, 0);
            }
        }
        __builtin_amdgcn_s_setprio(0);
    };

    // k-loop: 4 tiles / iteration, 2 barriers / iteration (~0.5 barrier/tile)
#pragma unroll 1
    for (int kt = 0; kt < KT; kt += 4) {
        if (kt + 2 < KT) prefetch(kt + 2, B0);
        if (kt + 3 < KT) prefetch(kt + 3, B1);
        compute(kt, A0, A0 + 8192);
        if (kt + 1 < KT) compute(kt + 1, A1, A1 + 8192);
        __syncthreads();
        if (kt + 2 >= KT) break;
        if (kt + 4 < KT) prefetch(kt + 4, A0);
        if (kt + 5 < KT) prefetch(kt + 5, A1);
        compute(kt + 2, B0, B0 + 8192);
        if (kt + 3 < KT) compute(kt + 3, B1, B1 + 8192);
        __syncthreads();
    }

    // epilogue: O^T/l -> per-wave LDS [q][d] -> coalesced 16B stores
#pragma unroll
    for (int which = 0; which < 2; ++which) {
        const floatx4* Oacc = which ? OaccB : OaccS;
        const float invl = 1.f / (which ? LaccB[0] : LaccS[0]);
        const int q0 = which ? q0B : q0S;
#pragma unroll
        for (int ds = 0; ds < 4; ++ds) {
            const int d = ds * 16 + quad * 4;
            uint2 ow;
            ow.x = pack2(Oacc[ds][0] * invl, Oacc[ds][1] * invl);
            ow.y = pack2(Oacc[ds][2] * invl, Oacc[ds][3] * invl);
            *reinterpret_cast<uint2*>(
                PsB + (d >> 3) * 256 + l15 * 16 + (d & 7) * 2) = ow;
        }
#pragma unroll
        for (int it = 0; it < 2; ++it) {
            const int idx = it * 64 + lane;
            const int chh = idx >> 4, q = idx & 15;
            short8 ov = *reinterpret_cast<const short8*>(PsB + chh * 256 + q * 16);
            *reinterpret_cast<short8*>(
                ob + (kvrow + q0 + w * 16 + q) * D_EMBED + h * 64 + chh * 8) = ov;
        }
    }
}

// ---------------------------------------------------------------------------
extern "C" void kernel_launch(void* const* d_in, const int* in_sizes, int n_in,
                              void* d_out, int out_size, void* d_ws, size_t ws_size,
                              hipStream_t stream)
{
    const float* x     = (const float*)d_in[0];   // [4096, 1024]
    const float* w_qkv = (const float*)d_in[1];   // [1024, 3072]
    const float* b_qkv = (const float*)d_in[2];   // [3072]
    const float* w_o   = (const float*)d_in[3];   // [1024, 1024]
    const float* b_o   = (const float*)d_in[4];   // [1024]
    float* out = (float*)d_out;                   // [4096, 1024] fp32

    bf16* xb     = (bf16*)d_ws;                    // [4096][1024]
    bf16* wqkvT  = xb + (size_t)4096 * 1024;       // [3072][1024]
    bf16* woT    = wqkvT + (size_t)3072 * 1024;    // [1024][1024]
    bf16* qbuf   = woT + (size_t)1024 * 1024;      // [4096][1024] (pre-scaled)
    bf16* kbuf   = qbuf + (size_t)4096 * 1024;     // [4096][1024]
    bf16* vtb    = kbuf + (size_t)4096 * 1024;     // [32 bh][64 d][2048 s]
    bf16* attnb  = vtb + (size_t)4096 * 1024;      // [4096][1024]

    dim3 blk(256);

    // fused casts (x-cast grid-strided x4; weight transpose unchanged)
    prep<<<dim3(2048), blk, 0, stream>>>(x, w_qkv, w_o, xb, wqkvT, woT);

    // QKV projection (q scaled, k row-major, V transposed directly), dbuf
    gemm_qkv<<<dim3(24, 32), blk, 0, stream>>>(xb, wqkvT, b_qkv, qbuf, kbuf, vtb);

    // flash attention: merged-pair causal blocks, dual-Ps interleave,
    // 4-buffer KV pipeline (2 tiles/barrier), setprio, complementary swizzle
    attn_mfma<<<dim3(512), blk, 0, stream>>>(qbuf, kbuf, vtb, attnb);

    // output projection (fp32 out + bias), 512 blocks, dbuf
    gemm_out<<<dim3(16, 32), blk, 0, stream>>>(attnb, woT, b_o, out);
}

// Round 10
// 171.892 us; speedup vs baseline: 1.0970x; 1.0089x over previous
//
#include <hip/hip_runtime.h>
#include <hip/hip_bf16.h>

typedef __hip_bfloat16 bf16;
typedef unsigned short u16;
typedef __attribute__((ext_vector_type(8))) short short8;
typedef __attribute__((ext_vector_type(4))) float floatx4;

#define D_EMBED 1024
#define N_HEADS 16
#define HEAD_DIM 64
#define BATCH 2
#define SEQ 2048
#define ROWS (BATCH * SEQ)          // 4096
#define QKV_COLS (3 * D_EMBED)      // 3072
// exp2-domain scale folded into Q: log2(e)/sqrt(64)
#define QSCALE 0.1803368801f

__device__ __forceinline__ void g2l16(const void* g, void* l) {
    __builtin_amdgcn_global_load_lds(
        (const __attribute__((address_space(1))) unsigned int*)g,
        (__attribute__((address_space(3))) unsigned int*)l,
        16, 0, 0);
}

__device__ __forceinline__ u16 f2b_bits(float f) {
    bf16 h = __float2bfloat16(f);
    u16 u;
    __builtin_memcpy(&u, &h, 2);
    return u;
}

__device__ __forceinline__ unsigned pack2(float a, float b) {   // RNE pack
    return (unsigned)f2b_bits(a) | ((unsigned)f2b_bits(b) << 16);
}

__device__ __forceinline__ float fexp2(float x) {
#if __has_builtin(__builtin_amdgcn_exp2f)
    return __builtin_amdgcn_exp2f(x);
#else
    return exp2f(x);
#endif
}

// pack two fp32 -> two truncated bf16 in one op (low = a, high = b)
__device__ __forceinline__ unsigned permpack(float a, float b) {
#if __has_builtin(__builtin_amdgcn_perm)
    return __builtin_amdgcn_perm(__float_as_uint(b), __float_as_uint(a), 0x07060302u);
#else
    return (__float_as_uint(a) >> 16) | (__float_as_uint(b) & 0xFFFF0000u);
#endif
}

// ---------------------------------------------------------------------------
// Fused prep: cast x -> bf16 (grid-stride, 4 float4/thread); transpose+cast
// w_qkv, w_o. Grid = 1024 (x-cast) + 1024 (weights) = 2048 blocks.
// ---------------------------------------------------------------------------
__global__ __launch_bounds__(256)
void prep(const float* __restrict__ x, const float* __restrict__ w_qkv,
          const float* __restrict__ w_o, bf16* __restrict__ xb,
          bf16* __restrict__ wqkvT, bf16* __restrict__ woT)
{
    __shared__ u16 T[64][72];
    const int tid = threadIdx.x;
    const int bid = blockIdx.x;

    if (bid < 1024) {
        // x-cast: 1024 blocks x 256 threads x 4 float4 = 4096*1024 floats
        const int t0 = bid * 256 + tid;
#pragma unroll
        for (int it = 0; it < 4; ++it) {
            const int i = t0 + it * 262144;
            const float4 v = reinterpret_cast<const float4*>(x)[i];
            ushort4 o;
            o.x = f2b_bits(v.x); o.y = f2b_bits(v.y);
            o.z = f2b_bits(v.z); o.w = f2b_bits(v.w);
            reinterpret_cast<ushort4*>(xb)[i] = o;
        }
        return;
    }
    const float* in; u16* out; int R, C, bx, by;
    if (bid < 1792) {
        const int t = bid - 1024;
        in = w_qkv; out = reinterpret_cast<u16*>(wqkvT); R = 1024; C = 3072;
        bx = t % 48; by = t / 48;
    } else {
        const int t = bid - 1792;
        in = w_o; out = reinterpret_cast<u16*>(woT); R = 1024; C = 1024;
        bx = t % 16; by = t / 16;
    }
    const int r0 = by * 64, c0 = bx * 64;
#pragma unroll
    for (int it = 0; it < 4; ++it) {
        const int r = (tid >> 4) + it * 16;
        const int c4 = (tid & 15) * 4;
        const float4 v = *reinterpret_cast<const float4*>(in + (size_t)(r0 + r) * C + c0 + c4);
        T[c4 + 0][r] = f2b_bits(v.x);
        T[c4 + 1][r] = f2b_bits(v.y);
        T[c4 + 2][r] = f2b_bits(v.z);
        T[c4 + 3][r] = f2b_bits(v.w);
    }
    __syncthreads();
#pragma unroll
    for (int it = 0; it < 4; ++it) {
        const int rr = (tid >> 4) + it * 16;
        const int cc4 = (tid & 15) * 4;
        ushort4 o = *reinterpret_cast<const ushort4*>(&T[rr][cc4]);
        *reinterpret_cast<ushort4*>(out + (size_t)(c0 + rr) * R + r0 + cc4) = o;
    }
}

// ---------------------------------------------------------------------------
// QKV MFMA GEMM: C[4096,3072] = A @ Bt^T + bias. 128x128 tile, BK=32,
// double-buffered staging (r6 version, g2l16 A from pre-cast xb).
// Epilogue: q (scaled) / k row-major bf16; V stored TRANSPOSED into
// vtb[bh*64+d][s] via per-wave LDS column reads.
// ---------------------------------------------------------------------------
__global__ __launch_bounds__(256)
void gemm_qkv(const bf16* __restrict__ A, const bf16* __restrict__ Bt,
              const float* __restrict__ bias,
              bf16* __restrict__ qb, bf16* __restrict__ kb, bf16* __restrict__ vtb)
{
    __shared__ __align__(16) char smem[32768];
    char* BUF0 = smem;            // As 8K + Bs 8K
    char* BUF1 = smem + 16384;

    const int tid = threadIdx.x;
    const int lane = tid & 63, w = tid >> 6;
    const int quad = lane >> 4, l15 = lane & 15;
    const int mw = (w >> 1) * 64, nw = (w & 1) * 64;
    const int blockM = blockIdx.y * 128, blockN = blockIdx.x * 128;

    const int row0 = tid >> 2, ch = tid & 3;
    const int off0 = (tid & ~63) * 16;
    const bf16* Asrc0 = A + (size_t)(blockM + row0) * 1024 + ch * 8;
    const bf16* Asrc1 = Asrc0 + (size_t)64 * 1024;
    const bf16* Bsrc0 = Bt + (size_t)(blockN + row0) * 1024 + ch * 8;
    const bf16* Bsrc1 = Bsrc0 + (size_t)64 * 1024;

    auto stage = [&](int k0, char* buf) {
        g2l16(Asrc0 + k0, buf + off0);
        g2l16(Asrc1 + k0, buf + off0 + 4096);
        g2l16(Bsrc0 + k0, buf + 8192 + off0);
        g2l16(Bsrc1 + k0, buf + 8192 + off0 + 4096);
    };

    floatx4 acc[4][4];
#pragma unroll
    for (int i = 0; i < 4; ++i)
#pragma unroll
        for (int j = 0; j < 4; ++j) acc[i][j] = (floatx4){0.f, 0.f, 0.f, 0.f};

    auto compute = [&](char* buf) {
        short8 af[4], bfr[4];
#pragma unroll
        for (int mi = 0; mi < 4; ++mi)
            af[mi] = *reinterpret_cast<const short8*>(
                buf + (mw + mi * 16 + l15) * 64 + quad * 16);
#pragma unroll
        for (int ni = 0; ni < 4; ++ni)
            bfr[ni] = *reinterpret_cast<const short8*>(
                buf + 8192 + (nw + ni * 16 + l15) * 64 + quad * 16);
#pragma unroll
        for (int mi = 0; mi < 4; ++mi)
#pragma unroll
            for (int ni = 0; ni < 4; ++ni)
                acc[mi][ni] = __builtin_amdgcn_mfma_f32_16x16x32_bf16(
                    af[mi], bfr[ni], acc[mi][ni], 0, 0, 0);
    };

    stage(0, BUF0);
    __syncthreads();
#pragma unroll 1
    for (int k0 = 0; k0 < 1024; k0 += 64) {
        if (k0 + 32 < 1024) stage(k0 + 32, BUF1);
        compute(BUF0);
        __syncthreads();
        if (k0 + 64 < 1024) stage(k0 + 64, BUF0);
        compute(BUF1);
        __syncthreads();
    }

    // epilogue: per-wave LDS repack
    u16* W = reinterpret_cast<u16*>(smem + w * 2304);   // [16 m][stride 72 u16]
    const bool isq = (blockN < 1024);
    const bool isv = (blockN >= 2048);

    float bvn[4];
#pragma unroll
    for (int ni = 0; ni < 4; ++ni) bvn[ni] = bias[blockN + nw + ni * 16 + l15];

    if (!isv) {
        bf16* dstbuf = isq ? qb : kb;
        const int coloff = blockN - (isq ? 0 : 1024);
#pragma unroll
        for (int mi = 0; mi < 4; ++mi) {
#pragma unroll
            for (int ni = 0; ni < 4; ++ni) {
#pragma unroll
                for (int r = 0; r < 4; ++r) {
                    float val = acc[mi][ni][r] + bvn[ni];
                    if (isq) val *= QSCALE;
                    W[(quad * 4 + r) * 72 + ni * 16 + l15] = f2b_bits(val);
                }
            }
#pragma unroll
            for (int half = 0; half < 2; ++half) {
                const int idx = half * 64 + lane;
                const int rowL = idx >> 3, chh = idx & 7;
                short8 v = *reinterpret_cast<const short8*>(W + rowL * 72 + chh * 8);
                const int grow = blockM + mw + mi * 16 + rowL;
                const int gcol = coloff + nw + chh * 8;
                *reinterpret_cast<short8*>(
                    reinterpret_cast<u16*>(dstbuf) + (size_t)grow * 1024 + gcol) = v;
            }
        }
    } else {
        const int col0 = blockN - 2048 + nw;          // multiple of 64
        const int h = col0 >> 6;
        const int bh = (blockM >> 11) * 16 + h;
        const int sb = (blockM & 2047) + mw;
        u16* vdst = reinterpret_cast<u16*>(vtb) + (size_t)bh * 64 * SEQ;
#pragma unroll
        for (int mi = 0; mi < 4; ++mi) {
#pragma unroll
            for (int ni = 0; ni < 4; ++ni) {
#pragma unroll
                for (int r = 0; r < 4; ++r)
                    W[(quad * 4 + r) * 72 + ni * 16 + l15] =
                        f2b_bits(acc[mi][ni][r] + bvn[ni]);
            }
#pragma unroll
            for (int mc = 0; mc < 2; ++mc) {
                u16 tmp[8];
#pragma unroll
                for (int e = 0; e < 8; ++e) tmp[e] = W[(mc * 8 + e) * 72 + lane];
                const int s = sb + mi * 16 + mc * 8;
                *reinterpret_cast<short8*>(vdst + (size_t)lane * SEQ + s) =
                    *reinterpret_cast<const short8*>(tmp);
            }
        }
    }
}

// ---------------------------------------------------------------------------
// Out-proj MFMA GEMM: out[4096,1024] = A @ Bt^T + bias (fp32 out).
// 128m x 64n tile -> 512 blocks (2/CU). Round 10: 4-buffer staging
// (2 x 32-k chunks per barrier interval, mirroring attn's r6 win).
// LDS = 4 x 12K = 48 KB -> still >=3 blocks/CU by LDS (grid caps at 2).
// Barriers: 32 -> 16; chunk order unchanged -> bitwise identical.
// K=1024 = exactly 8 iterations of 4 chunks (no compute guards needed).
// ---------------------------------------------------------------------------
__global__ __launch_bounds__(256)
void gemm_out(const bf16* __restrict__ A, const bf16* __restrict__ Bt,
              const float* __restrict__ bias, float* __restrict__ outf)
{
    __shared__ __align__(16) char smem[49152];
    char* A0 = smem;              // As 8K + Bs 4K
    char* A1 = smem + 12288;
    char* B0 = smem + 24576;
    char* B1 = smem + 36864;

    const int tid = threadIdx.x;
    const int lane = tid & 63, w = tid >> 6;
    const int quad = lane >> 4, l15 = lane & 15;
    const int mw = (w >> 1) * 64, nw = (w & 1) * 32;
    const int blockM = blockIdx.y * 128, blockN = blockIdx.x * 64;

    const int row0 = tid >> 2, ch = tid & 3;
    const int off0 = (tid & ~63) * 16;
    const bf16* Asrc0 = A + (size_t)(blockM + row0) * 1024 + ch * 8;
    const bf16* Asrc1 = Asrc0 + (size_t)64 * 1024;
    const bf16* Bsrc0 = Bt + (size_t)(blockN + row0) * 1024 + ch * 8;

    auto stage = [&](int k0, char* buf) {
        g2l16(Asrc0 + k0, buf + off0);
        g2l16(Asrc1 + k0, buf + off0 + 4096);
        g2l16(Bsrc0 + k0, buf + 8192 + off0);
    };

    floatx4 acc[4][2];
#pragma unroll
    for (int i = 0; i < 4; ++i)
#pragma unroll
        for (int j = 0; j < 2; ++j) acc[i][j] = (floatx4){0.f, 0.f, 0.f, 0.f};

    auto compute = [&](char* buf) {
        short8 af[4], bfr[2];
#pragma unroll
        for (int mi = 0; mi < 4; ++mi)
            af[mi] = *reinterpret_cast<const short8*>(
                buf + (mw + mi * 16 + l15) * 64 + quad * 16);
#pragma unroll
        for (int ni = 0; ni < 2; ++ni)
            bfr[ni] = *reinterpret_cast<const short8*>(
                buf + 8192 + (nw + ni * 16 + l15) * 64 + quad * 16);
#pragma unroll
        for (int mi = 0; mi < 4; ++mi)
#pragma unroll
            for (int ni = 0; ni < 2; ++ni)
                acc[mi][ni] = __builtin_amdgcn_mfma_f32_16x16x32_bf16(
                    af[mi], bfr[ni], acc[mi][ni], 0, 0, 0);
    };

    // prologue: chunks 0,32 into A0,A1
    stage(0, A0);
    stage(32, A1);
    __syncthreads();
#pragma unroll 1
    for (int k0 = 0; k0 < 1024; k0 += 128) {
        if (k0 + 64 < 1024) stage(k0 + 64, B0);
        if (k0 + 96 < 1024) stage(k0 + 96, B1);
        compute(A0);
        compute(A1);
        __syncthreads();
        if (k0 + 128 < 1024) stage(k0 + 128, A0);
        if (k0 + 160 < 1024) stage(k0 + 160, A1);
        compute(B0);
        compute(B1);
        __syncthreads();
    }

    float bvn[2];
#pragma unroll
    for (int ni = 0; ni < 2; ++ni) bvn[ni] = bias[blockN + nw + ni * 16 + l15];

#pragma unroll
    for (int mi = 0; mi < 4; ++mi)
#pragma unroll
        for (int r = 0; r < 4; ++r) {
            const int row = blockM + mw + mi * 16 + quad * 4 + r;
#pragma unroll
            for (int ni = 0; ni < 2; ++ni) {
                const int col = blockN + nw + ni * 16 + l15;
                outf[(size_t)row * 1024 + col] = acc[mi][ni][r] + bvn[ni];
            }
        }
}

// ---------------------------------------------------------------------------
// MFMA flash attention (causal), max-free exp2-domain softmax.
// EXACT r6 kernel (best measured: 172.9 us total): merged-pair shell,
// 4-buffer KV pipeline (2 tiles/barrier), setprio, complementary swizzle.
// LDS: 4 x 16K KV + 16K Ps = 80 KB (2 blocks/CU).
// ---------------------------------------------------------------------------
__global__ __launch_bounds__(256)
void attn_mfma(const bf16* __restrict__ qb, const bf16* __restrict__ kb,
               const bf16* __restrict__ vtb, bf16* __restrict__ ob)
{
    __shared__ __align__(16) char smem[81920];
    char* A0 = smem;                      // K 8K + V 8K  (tiles kt%4==0)
    char* A1 = smem + 16384;              // tiles kt%4==1
    char* B0 = smem + 32768;              // tiles kt%4==2 (initially Q staging)
    char* B1 = smem + 49152;              // tiles kt%4==3
    const int tid = threadIdx.x;
    const int lane = tid & 63, w = tid >> 6;
    const int quad = lane >> 4, l15 = lane & 15;
    char* PsB = smem + 65536 + w * 2048;  // per-wave [8 kchunk][16 q][16B]
    char* PsS = smem + 73728 + w * 2048;

    // complementary swizzle: l and l+256 share a CU (round-robin heuristic)
    // slot<8: pi=slot ; slot>=8: pi=23-slot  => KT(l) + KT(l+256) = 49
    const int l = blockIdx.x;
    const int bh = l & 31;
    const int slot = l >> 5;
    const int pi = (slot < 8) ? slot : 23 - slot;
    const int b = bh >> 4, h = bh & 15;

    const int qtS = pi, qtB = 31 - pi;
    const int q0S = qtS * 64, q0B = qtB * 64;
    const int KT = qtB + 1;               // 17..32
    const int qrowS = q0S + w * 16 + l15;
    const int qrowB = q0B + w * 16 + l15;

    const size_t kvrow = (size_t)b * SEQ;
    const size_t vbase = (size_t)bh * 64 * SEQ;

    const short8 ones = {0x3F80, 0x3F80, 0x3F80, 0x3F80,
                         0x3F80, 0x3F80, 0x3F80, 0x3F80};   // bf16 1.0 x8

    // hoisted staging geometry: row1 = row0+32, lch identical (32 % 8 == 0)
    const int row0 = tid >> 3;
    const int lch = (tid & 7) ^ (row0 & 7);
    const int loff0 = (tid & ~63) * 16;
    const int loff1 = loff0 + 4096;
    const bf16* ksrc0 = kb + (kvrow + row0) * D_EMBED + h * 64 + lch * 8;
    const bf16* ksrc1 = ksrc0 + (size_t)32 * D_EMBED;
    const bf16* vsrc0 = vtb + vbase + (size_t)row0 * SEQ + lch * 8;
    const bf16* vsrc1 = vsrc0 + (size_t)32 * SEQ;

    auto prefetch = [&](int nkt, char* dst) {
        const size_t ko = (size_t)nkt * 64;
        g2l16(ksrc0 + ko * D_EMBED, dst + loff0);
        g2l16(ksrc1 + ko * D_EMBED, dst + loff1);
        g2l16(vsrc0 + ko, dst + 8192 + loff0);
        g2l16(vsrc1 + ko, dst + 8192 + loff1);
    };

    // stage Q tiles into B0 (dead after fragment load) + K/V tiles 0,1
    {
        const bf16* qsrcS = qb + (kvrow + q0S + row0) * D_EMBED + h * 64 + lch * 8;
        const bf16* qsrcB = qb + (kvrow + q0B + row0) * D_EMBED + h * 64 + lch * 8;
        g2l16(qsrcS, B0 + loff0);
        g2l16(qsrcS + (size_t)32 * D_EMBED, B0 + loff1);
        g2l16(qsrcB, B0 + 8192 + loff0);
        g2l16(qsrcB + (size_t)32 * D_EMBED, B0 + 8192 + loff1);
        prefetch(0, A0);
        prefetch(1, A1);          // KT >= 17, tile 1 always exists
    }
    __syncthreads();

    const int qoff = (w * 16 + l15) * 128;
    const int x0 = (quad ^ (l15 & 7)) * 16;
    const int x1 = ((quad + 4) ^ (l15 & 7)) * 16;
    const short8 qS0 = *reinterpret_cast<const short8*>(B0 + qoff + x0);
    const short8 qS1 = *reinterpret_cast<const short8*>(B0 + qoff + x1);
    const short8 qB0 = *reinterpret_cast<const short8*>(B0 + 8192 + qoff + x0);
    const short8 qB1 = *reinterpret_cast<const short8*>(B0 + 8192 + qoff + x1);
    __syncthreads();    // Q reads done; B0 free for prefetch

    floatx4 OaccS[4], OaccB[4], LaccS, LaccB;
#pragma unroll
    for (int i = 0; i < 4; ++i) {
        OaccS[i] = (floatx4){0.f, 0.f, 0.f, 0.f};
        OaccB[i] = (floatx4){0.f, 0.f, 0.f, 0.f};
    }
    LaccS = (floatx4){0.f, 0.f, 0.f, 0.f};
    LaccB = (floatx4){0.f, 0.f, 0.f, 0.f};

    // interleaved dual-q compute: both chains issued together
    auto compute = [&](int kt, char* Ks, char* Vs) {
        const int k0 = kt * 64;
        const bool doS = (kt <= qtS);
        short8 kf[2][4], vf[2][4];
#pragma unroll
        for (int ms = 0; ms < 4; ++ms) {
            const int roff = (ms * 16 + l15) * 128;
            kf[0][ms] = *reinterpret_cast<const short8*>(Ks + roff + x0);
            kf[1][ms] = *reinterpret_cast<const short8*>(Ks + roff + x1);
        }
#pragma unroll
        for (int ks = 0; ks < 2; ++ks)
#pragma unroll
            for (int ds = 0; ds < 4; ++ds)
                vf[ks][ds] = *reinterpret_cast<const short8*>(
                    Vs + (ds * 16 + l15) * 128 + (((quad + ks * 4) ^ (l15 & 7)) * 16));

        // S MFMAs for both tiles (independent)
        floatx4 SB[4], SS[4];
        __builtin_amdgcn_s_setprio(1);
#pragma unroll
        for (int ms = 0; ms < 4; ++ms) {
            floatx4 t = (floatx4){0.f, 0.f, 0.f, 0.f};
            t = __builtin_amdgcn_mfma_f32_16x16x32_bf16(kf[0][ms], qB0, t, 0, 0, 0);
            SB[ms] = __builtin_amdgcn_mfma_f32_16x16x32_bf16(kf[1][ms], qB1, t, 0, 0, 0);
        }
        if (doS) {
#pragma unroll
            for (int ms = 0; ms < 4; ++ms) {
                floatx4 t = (floatx4){0.f, 0.f, 0.f, 0.f};
                t = __builtin_amdgcn_mfma_f32_16x16x32_bf16(kf[0][ms], qS0, t, 0, 0, 0);
                SS[ms] = __builtin_amdgcn_mfma_f32_16x16x32_bf16(kf[1][ms], qS1, t, 0, 0, 0);
            }
        }
        __builtin_amdgcn_s_setprio(0);

        // exp + Ps writes: big -> PsB, small -> PsS (disjoint regions)
        const bool diagB = (kt == KT - 1);
#pragma unroll
        for (int ms = 0; ms < 4; ++ms) {
            float p[4];
#pragma unroll
            for (int r = 0; r < 4; ++r) {
                float s = SB[ms][r];
                if (diagB && (k0 + ms * 16 + quad * 4 + r) > qrowB) s = -1e30f;
                p[r] = fexp2(s);
            }
            const int k = ms * 16 + quad * 4;
            uint2 pw;
            pw.x = permpack(p[0], p[1]);
            pw.y = permpack(p[2], p[3]);
            *reinterpret_cast<uint2*>(PsB + (k >> 3) * 256 + l15 * 16 + (k & 7) * 2) = pw;
        }
        if (doS) {
            const bool diagS = (kt == qtS);
#pragma unroll
            for (int ms = 0; ms < 4; ++ms) {
                float p[4];
#pragma unroll
                for (int r = 0; r < 4; ++r) {
                    float s = SS[ms][r];
                    if (diagS && (k0 + ms * 16 + quad * 4 + r) > qrowS) s = -1e30f;
                    p[r] = fexp2(s);
                }
                const int k = ms * 16 + quad * 4;
                uint2 pw;
                pw.x = permpack(p[0], p[1]);
                pw.y = permpack(p[2], p[3]);
                *reinterpret_cast<uint2*>(PsS + (k >> 3) * 256 + l15 * 16 + (k & 7) * 2) = pw;
            }
        }

        // O MFMAs, both chains interleaved
        __builtin_amdgcn_s_setprio(1);
#pragma unroll
        for (int ks = 0; ks < 2; ++ks) {
            const short8 pfB = *reinterpret_cast<const short8*>(
                PsB + (ks * 4 + quad) * 256 + l15 * 16);
            LaccB = __builtin_amdgcn_mfma_f32_16x16x32_bf16(ones, pfB, LaccB, 0, 0, 0);
#pragma unroll
            for (int ds = 0; ds < 4; ++ds)
                OaccB[ds] = __builtin_amdgcn_mfma_f32_16x16x32_bf16(
                    vf[ks][ds], pfB, OaccB[ds], 0, 0, 0);
            if (doS) {
                const short8 pfS = *reinterpret_cast<const short8*>(
                    PsS + (ks * 4 + quad) * 256 + l15 * 16);
                LaccS = __builtin_amdgcn_mfma_f32_16x16x32_bf16(ones, pfS, LaccS, 0, 0, 0);
#pragma unroll
                for (int ds = 0; ds < 4; ++ds)
                    OaccS[ds] = __builtin_amdgcn_mfma_f32_16x16x32_bf16(
                        vf[ks][ds], pfS, OaccS[ds], 0, 0, 0);
            }
        }
        __builtin_amdgcn_s_setprio(0);
    };

    // k-loop: 4 tiles / iteration, 2 barriers / iteration (~0.5 barrier/tile)
#pragma unroll 1
    for (int kt = 0; kt < KT; kt += 4) {
        if (kt + 2 < KT) prefetch(kt + 2, B0);
        if (kt + 3 < KT) prefetch(kt + 3, B1);
        compute(kt, A0, A0 + 8192);
        if (kt + 1 < KT) compute(kt + 1, A1, A1 + 8192);
        __syncthreads();
        if (kt + 2 >= KT) break;
        if (kt + 4 < KT) prefetch(kt + 4, A0);
        if (kt + 5 < KT) prefetch(kt + 5, A1);
        compute(kt + 2, B0, B0 + 8192);
        if (kt + 3 < KT) compute(kt + 3, B1, B1 + 8192);
        __syncthreads();
    }

    // epilogue: O^T/l -> per-wave LDS [q][d] -> coalesced 16B stores
#pragma unroll
    for (int which = 0; which < 2; ++which) {
        const floatx4* Oacc = which ? OaccB : OaccS;
        const float invl = 1.f / (which ? LaccB[0] : LaccS[0]);
        const int q0 = which ? q0B : q0S;
#pragma unroll
        for (int ds = 0; ds < 4; ++ds) {
            const int d = ds * 16 + quad * 4;
            uint2 ow;
            ow.x = pack2(Oacc[ds][0] * invl, Oacc[ds][1] * invl);
            ow.y = pack2(Oacc[ds][2] * invl, Oacc[ds][3] * invl);
            *reinterpret_cast<uint2*>(
                PsB + (d >> 3) * 256 + l15 * 16 + (d & 7) * 2) = ow;
        }
#pragma unroll
        for (int it = 0; it < 2; ++it) {
            const int idx = it * 64 + lane;
            const int chh = idx >> 4, q = idx & 15;
            short8 ov = *reinterpret_cast<const short8*>(PsB + chh * 256 + q * 16);
            *reinterpret_cast<short8*>(
                ob + (kvrow + q0 + w * 16 + q) * D_EMBED + h * 64 + chh * 8) = ov;
        }
    }
}

// ---------------------------------------------------------------------------
extern "C" void kernel_launch(void* const* d_in, const int* in_sizes, int n_in,
                              void* d_out, int out_size, void* d_ws, size_t ws_size,
                              hipStream_t stream)
{
    const float* x     = (const float*)d_in[0];   // [4096, 1024]
    const float* w_qkv = (const float*)d_in[1];   // [1024, 3072]
    const float* b_qkv = (const float*)d_in[2];   // [3072]
    const float* w_o   = (const float*)d_in[3];   // [1024, 1024]
    const float* b_o   = (const float*)d_in[4];   // [1024]
    float* out = (float*)d_out;                   // [4096, 1024] fp32

    bf16* xb     = (bf16*)d_ws;                    // [4096][1024]
    bf16* wqkvT  = xb + (size_t)4096 * 1024;       // [3072][1024]
    bf16* woT    = wqkvT + (size_t)3072 * 1024;    // [1024][1024]
    bf16* qbuf   = woT + (size_t)1024 * 1024;      // [4096][1024] (pre-scaled)
    bf16* kbuf   = qbuf + (size_t)4096 * 1024;     // [4096][1024]
    bf16* vtb    = kbuf + (size_t)4096 * 1024;     // [32 bh][64 d][2048 s]
    bf16* attnb  = vtb + (size_t)4096 * 1024;      // [4096][1024]

    dim3 blk(256);

    // fused casts (x-cast grid-strided x4; weight transpose unchanged)
    prep<<<dim3(2048), blk, 0, stream>>>(x, w_qkv, w_o, xb, wqkvT, woT);

    // QKV projection (q scaled, k row-major, V transposed directly), dbuf
    gemm_qkv<<<dim3(24, 32), blk, 0, stream>>>(xb, wqkvT, b_qkv, qbuf, kbuf, vtb);

    // flash attention: merged-pair causal blocks, dual-Ps interleave,
    // 4-buffer KV pipeline (2 tiles/barrier), setprio, complementary swizzle
    attn_mfma<<<dim3(512), blk, 0, stream>>>(qbuf, kbuf, vtb, attnb);

    // output projection (fp32 out + bias), 512 blocks, 4-buffer staging
    gemm_out<<<dim3(16, 32), blk, 0, stream>>>(attnb, woT, b_o, out);
}